// Round 5
// baseline (113.353 us; speedup 1.0000x reference)
//
#include <hip/hip_runtime.h>
#include <hip/hip_bf16.h>

// Problem constants (B=1)
#define NTOK   384
#define DNODE  256
#define DPAIR  128
#define DHID   32
#define NOUT   49152   // NTOK * DPAIR, columns (fast axis) of the output
static constexpr float LN_EPS = 1e-5f;

typedef __bf16 bf16x8 __attribute__((ext_vector_type(8)));
typedef __bf16 bf16x4 __attribute__((ext_vector_type(4)));
typedef float  f32x4  __attribute__((ext_vector_type(4)));

// ---------------------------------------------------------------------------
// Kernel 1: LayerNorm + projections a = sn@Wa^T + ba, b = sn@Wb^T + bb
//           (one block per token row). Outputs bf16 [384][32] each.
// ---------------------------------------------------------------------------
__global__ __launch_bounds__(256) void k1_ln_proj(
    const float* __restrict__ s, const float* __restrict__ gamma,
    const float* __restrict__ beta,
    const float* __restrict__ Wa, const float* __restrict__ ba,
    const float* __restrict__ Wb, const float* __restrict__ bb,
    __bf16* __restrict__ a_vec, __bf16* __restrict__ b_vec)
{
    const int t = threadIdx.x;
    const int blk = blockIdx.x;

    __shared__ __align__(16) float sn[DNODE];
    __shared__ float red[8];

    const float x = s[blk * DNODE + t];
    float v0 = x, v1 = x * x;
    #pragma unroll
    for (int off = 32; off > 0; off >>= 1) {
        v0 += __shfl_down(v0, off, 64);
        v1 += __shfl_down(v1, off, 64);
    }
    if ((t & 63) == 0) { red[(t >> 6) * 2] = v0; red[(t >> 6) * 2 + 1] = v1; }
    __syncthreads();
    const float sum   = red[0] + red[2] + red[4] + red[6];
    const float sumsq = red[1] + red[3] + red[5] + red[7];
    const float mu  = sum * (1.0f / DNODE);
    const float var = sumsq * (1.0f / DNODE) - mu * mu;
    const float inv = rsqrtf(var + LN_EPS);
    sn[t] = (x - mu) * inv * gamma[t] + beta[t];
    __syncthreads();

    // 64 outputs (32 for a, 32 for b); 4 threads per output, 64 terms each.
    const int o = t >> 2, part = t & 3;
    const float* Wrow = (o < DHID) ? (Wa + (size_t)o * DNODE)
                                   : (Wb + (size_t)(o - DHID) * DNODE);
    const int base = part * 64;
    float acc = 0.f;
    #pragma unroll
    for (int k = 0; k < 64; k += 4) {
        const float4 w  = *(const float4*)(Wrow + base + k);
        const float4 xs = *(const float4*)(sn + base + k);
        acc += w.x * xs.x + w.y * xs.y + w.z * xs.z + w.w * xs.w;
    }
    acc += __shfl_xor(acc, 1, 64);
    acc += __shfl_xor(acc, 2, 64);
    if (part == 0) {
        if (o < DHID) a_vec[blk * DHID + o]          = (__bf16)(acc + ba[o]);
        else          b_vec[blk * DHID + (o - DHID)] = (__bf16)(acc + bb[o - DHID]);
    }
}

// ---------------------------------------------------------------------------
// Kernel 2: T[j, m] = sum_e Wo[m, e] * b[j, e], m = (p,d) in [0,4096)
// MFMA with M = m (Wo rows as A-operand, fp32->bf16 inline), N = j.
// Tm layout: [j][4096] row-major == flat (j*128+p)*32 + d.
// ---------------------------------------------------------------------------
__global__ __launch_bounds__(256) void k2_build_T(
    const __bf16* __restrict__ b_vec, const float* __restrict__ Wo,
    __bf16* __restrict__ Tm)
{
    const int l = threadIdx.x & 63;
    const int w = threadIdx.x >> 6;
    const int j0 = blockIdx.y * 16;
    const int mg = blockIdx.x * 4 + w;        // m-group: 4 consecutive m-tiles
    const int row = l & 15, q = l >> 4, koff = q * 8;

    // B-operand: b rows (n = j), loaded once per wave
    const bf16x8 bfr = *(const bf16x8*)(b_vec + (j0 + row) * DHID + koff);

    #pragma unroll
    for (int tt = 0; tt < 4; ++tt) {
        const int m0 = (mg * 4 + tt) * 16;
        // A-operand: Wo rows (m = (p,d)), fp32 -> bf16 inline
        const float* wr = Wo + (size_t)(m0 + row) * 32 + koff;
        const float4 w0 = *(const float4*)(wr);
        const float4 w1 = *(const float4*)(wr + 4);
        bf16x8 afr;
        afr[0] = (__bf16)w0.x; afr[1] = (__bf16)w0.y;
        afr[2] = (__bf16)w0.z; afr[3] = (__bf16)w0.w;
        afr[4] = (__bf16)w1.x; afr[5] = (__bf16)w1.y;
        afr[6] = (__bf16)w1.z; afr[7] = (__bf16)w1.w;

        f32x4 acc = {0.f, 0.f, 0.f, 0.f};
        acc = __builtin_amdgcn_mfma_f32_16x16x32_bf16(afr, bfr, acc, 0, 0, 0);

        bf16x4 o;
        o[0] = (__bf16)acc[0]; o[1] = (__bf16)acc[1];
        o[2] = (__bf16)acc[2]; o[3] = (__bf16)acc[3];
        *(bf16x4*)(Tm + (size_t)(j0 + row) * 4096 + m0 + q * 4) = o;
    }
}

// ---------------------------------------------------------------------------
// Kernel 3: out[i, jp] = sum_d T[jp, d] * a[i, d] + bo[jp & 127]
// MFMA with M = jp (T rows as A-operand), N = i (a rows as B-operand).
// R5: block = 32 i-rows x 256 jp-cols; grid x = i-group (FAST axis) so the
// ~12 consecutively-dispatched blocks share one 16-KB Tm slice -> each slice
// is L2-read once per XCD inside a tight temporal window, before the 75.5-MB
// write stream evicts it (Tm re-read amplification 24x -> ~8x). Each Tm
// fragment load now feeds 2 MFMAs (two i-tiles). Epilogue unchanged: LDS
// transpose then 1-KB fully-contiguous cached wave stores.
// ---------------------------------------------------------------------------
__global__ __launch_bounds__(256) void k3_main(
    const __bf16* __restrict__ a_vec, const __bf16* __restrict__ Tm,
    const float* __restrict__ bo, float* __restrict__ out)
{
    __shared__ __align__(16) float tilebuf[32][260];   // 33.3 KB -> 4 blk/CU
    const int l = threadIdx.x & 63;
    const int w = threadIdx.x >> 6;
    const int i0 = blockIdx.x * 32;          // x = i-group (12), fast axis
    const int jpbase = blockIdx.y * 256;     // y = jp-group (192)
    const int row = l & 15, q = l >> 4, koff = q * 8;

    // B-operand fragments: a rows for the two i-tiles
    const bf16x8 af0 = *(const bf16x8*)(a_vec + (i0 + row) * DHID + koff);
    const bf16x8 af1 = *(const bf16x8*)(a_vec + (i0 + 16 + row) * DHID + koff);

    #pragma unroll
    for (int tt = 0; tt < 4; ++tt) {
        const int jpl = w * 64 + tt * 16;       // jp offset within block span
        const int jp0 = jpbase + jpl;
        // A-operand: T rows (m = jp), loaded ONCE, feeds both i-tiles
        const bf16x8 tfr = *(const bf16x8*)(Tm + (size_t)(jp0 + row) * 32 + koff);
        const float4 bv = *(const float4*)(bo + ((jpl & (DPAIR - 1)) + q * 4));
        f32x4 acc0 = {bv.x, bv.y, bv.z, bv.w};
        f32x4 acc1 = acc0;
        acc0 = __builtin_amdgcn_mfma_f32_16x16x32_bf16(tfr, af0, acc0, 0, 0, 0);
        acc1 = __builtin_amdgcn_mfma_f32_16x16x32_bf16(tfr, af1, acc1, 0, 0, 0);
        // lane holds out[i0(+16)+row][jp0 + q*4 .. +3]
        *(f32x4*)&tilebuf[row][jpl + q * 4]      = acc0;
        *(f32x4*)&tilebuf[16 + row][jpl + q * 4] = acc1;
    }
    __syncthreads();

    // Store 32 rows x 1 KB; wave w handles rows {w, 4+w, ..., 28+w}.
    #pragma unroll
    for (int rr = 0; rr < 8; ++rr) {
        const int r = rr * 4 + w;
        const f32x4 v = *(const f32x4*)&tilebuf[r][l * 4];
        *(f32x4*)(out + (size_t)(i0 + r) * NOUT + jpbase + l * 4) = v;
    }
}

// ---------------------------------------------------------------------------
extern "C" void kernel_launch(void* const* d_in, const int* in_sizes, int n_in,
                              void* d_out, int out_size, void* d_ws, size_t ws_size,
                              hipStream_t stream)
{
    const float* s     = (const float*)d_in[0];
    const float* gamma = (const float*)d_in[1];
    const float* beta  = (const float*)d_in[2];
    const float* Wa    = (const float*)d_in[3];
    const float* ba    = (const float*)d_in[4];
    const float* Wb    = (const float*)d_in[5];
    const float* bb    = (const float*)d_in[6];
    const float* Wo    = (const float*)d_in[7];
    const float* bo    = (const float*)d_in[8];
    float* out = (float*)d_out;

    // Workspace layout (16B-aligned), total ~3.2 MB:
    char* ws = (char*)d_ws;
    __bf16* a_vec = (__bf16*)(ws);            // 384*32*2   = 24576 B
    __bf16* b_vec = (__bf16*)(ws + 24576);    // 384*32*2   = 24576 B
    __bf16* Tm    = (__bf16*)(ws + 49152);    // 384*4096*2 = 3145728 B

    // K1: 384 LN/proj blocks
    k1_ln_proj<<<384, 256, 0, stream>>>(s, gamma, beta, Wa, ba, Wb, bb,
                                        a_vec, b_vec);
    // K2: T  (M=4096 (p,d), N=384 j, K=32 e): 256 m-tiles x 24 j-tiles
    k2_build_T<<<dim3(16, 24), 256, 0, stream>>>(b_vec, Wo, Tm);
    // K3: out: x = 12 i-groups (32 rows), y = 192 jp-groups (256 cols).
    //     x is the fast dispatch axis -> temporal Tm-slice sharing.
    k3_main<<<dim3(12, 192), 256, 0, stream>>>(a_vec, Tm, bo, out);
}